// Round 1
// baseline (1164.629 us; speedup 1.0000x reference)
//
#include <hip/hip_runtime.h>

// Flash-attention fwd, B=4 H=16 S=2048 D=128, fp32 in/out, bf16 MFMA compute.
// Round 1: correctness-first. Known deferred opts: V-transpose staging uses
// scalar u16 LDS writes (bank conflicts), mask loaded per-element, no
// global_load_lds, no double buffer.

#define S_LEN 2048
#define HD 128
#define BQ 64
#define BK 64
#define KLD 136   // K LDS row stride (bf16 elems), mult-of-8 for b128 align, 2-way banks
#define VLD 72    // V^T LDS row stride
#define PLD 72    // P LDS row stride

typedef __attribute__((ext_vector_type(8))) short bf16x8;
typedef __attribute__((ext_vector_type(4))) float f32x4;
typedef __attribute__((ext_vector_type(4))) short s16x4;

static __device__ __forceinline__ unsigned short f2bf(float f) {
    unsigned int u = __builtin_bit_cast(unsigned int, f);
    u += 0x7fffu + ((u >> 16) & 1u);   // round-to-nearest-even
    return (unsigned short)(u >> 16);
}

__global__ __launch_bounds__(256, 2)
void fattn_kernel(const float* __restrict__ qg0, const float* __restrict__ kg0,
                  const float* __restrict__ vg0, const float* __restrict__ maskg,
                  float* __restrict__ outg0)
{
    __shared__ short k_lds[BK * KLD];       // K tile, row-major [kk][d]
    __shared__ short vt_lds[HD * VLD];      // V tile, transposed [d][kk]
    __shared__ short p_lds[4 * 16 * PLD];   // per-wave P tile [16][BK]

    const int tid  = threadIdx.x;
    const int wave = tid >> 6;
    const int lane = tid & 63;
    const int quad = lane >> 4;
    const int l16  = lane & 15;

    const int q0 = blockIdx.x * BQ;
    const int bh = blockIdx.y;

    const float* qg   = qg0 + (size_t)bh * S_LEN * HD;
    const float* kg   = kg0 + (size_t)bh * S_LEN * HD;
    const float* vg   = vg0 + (size_t)bh * S_LEN * HD;
    float*       outg = outg0 + (size_t)bh * S_LEN * HD;

    // Q A-fragments: m = l16 (row within wave tile), k = ks*32 + quad*8 + j
    bf16x8 qf[4];
    {
        const float* qrow = qg + (size_t)(q0 + wave * 16 + l16) * HD + quad * 8;
        #pragma unroll
        for (int ks = 0; ks < 4; ++ks)
            #pragma unroll
            for (int j = 0; j < 8; ++j)
                qf[ks][j] = (short)f2bf(qrow[ks * 32 + j]);
    }

    float m_run[4], l_run[4];
    f32x4 oacc[8];
    #pragma unroll
    for (int r = 0; r < 4; ++r) { m_run[r] = -3.0e38f; l_run[r] = 0.0f; }
    #pragma unroll
    for (int d = 0; d < 8; ++d) oacc[d] = (f32x4){0.f, 0.f, 0.f, 0.f};

    const float scale = 0.088388347648318447f;  // 1/sqrt(128)
    const float* mrow = maskg + (size_t)(q0 + wave * 16 + quad * 4) * S_LEN + l16;

    for (int kt = 0; kt < S_LEN / BK; ++kt) {
        const int kbase = kt * BK;
        __syncthreads();   // previous iter's LDS reads done before restage
        // ---- stage K (row-major bf16) and V (transposed bf16) ----
        {
            const int rr = tid >> 5;          // 0..7
            const int c4 = (tid & 31) * 4;    // 0,4,...,124
            #pragma unroll
            for (int it = 0; it < 8; ++it) {
                const int row = rr + it * 8;
                const float4 kv4 = *(const float4*)(kg + (size_t)(kbase + row) * HD + c4);
                s16x4 kb4;
                kb4[0] = (short)f2bf(kv4.x); kb4[1] = (short)f2bf(kv4.y);
                kb4[2] = (short)f2bf(kv4.z); kb4[3] = (short)f2bf(kv4.w);
                *(s16x4*)&k_lds[row * KLD + c4] = kb4;
                const float4 vv4 = *(const float4*)(vg + (size_t)(kbase + row) * HD + c4);
                vt_lds[(c4 + 0) * VLD + row] = (short)f2bf(vv4.x);
                vt_lds[(c4 + 1) * VLD + row] = (short)f2bf(vv4.y);
                vt_lds[(c4 + 2) * VLD + row] = (short)f2bf(vv4.z);
                vt_lds[(c4 + 3) * VLD + row] = (short)f2bf(vv4.w);
            }
        }
        __syncthreads();

        // ---- S = (Q K^T)*scale + mask ----
        f32x4 sf[4];
        #pragma unroll
        for (int nt = 0; nt < 4; ++nt) {
            f32x4 acc = (f32x4){0.f, 0.f, 0.f, 0.f};
            #pragma unroll
            for (int ks = 0; ks < 4; ++ks) {
                const bf16x8 kf =
                    *(const bf16x8*)&k_lds[(nt * 16 + l16) * KLD + ks * 32 + quad * 8];
                acc = __builtin_amdgcn_mfma_f32_16x16x32_bf16(qf[ks], kf, acc, 0, 0, 0);
            }
            sf[nt] = acc;
        }

        float sv[4][4];
        float mx[4] = {-3.0e38f, -3.0e38f, -3.0e38f, -3.0e38f};
        #pragma unroll
        for (int nt = 0; nt < 4; ++nt)
            #pragma unroll
            for (int r = 0; r < 4; ++r) {
                const float s = sf[nt][r] * scale + mrow[(size_t)r * S_LEN + kbase + nt * 16];
                sv[nt][r] = s;
                mx[r] = fmaxf(mx[r], s);
            }
        #pragma unroll
        for (int r = 0; r < 4; ++r) {  // row lives in 16 lanes of the quad group
            mx[r] = fmaxf(mx[r], __shfl_xor(mx[r], 1, 16));
            mx[r] = fmaxf(mx[r], __shfl_xor(mx[r], 2, 16));
            mx[r] = fmaxf(mx[r], __shfl_xor(mx[r], 4, 16));
            mx[r] = fmaxf(mx[r], __shfl_xor(mx[r], 8, 16));
        }

        float alpha[4], pl[4];
        #pragma unroll
        for (int r = 0; r < 4; ++r) {
            const float mnew = fmaxf(m_run[r], mx[r]);
            alpha[r] = __expf(m_run[r] - mnew);
            m_run[r] = mnew;
            pl[r] = 0.f;
        }

        short pb[4][4];
        #pragma unroll
        for (int nt = 0; nt < 4; ++nt)
            #pragma unroll
            for (int r = 0; r < 4; ++r) {
                const float p = __expf(sv[nt][r] - m_run[r]);
                const unsigned short b = f2bf(p);
                pb[nt][r] = (short)b;
                // accumulate l from the *rounded* p so normalization matches PV
                pl[r] += __builtin_bit_cast(float, (unsigned int)b << 16);
            }
        #pragma unroll
        for (int r = 0; r < 4; ++r) {
            pl[r] += __shfl_xor(pl[r], 1, 16);
            pl[r] += __shfl_xor(pl[r], 2, 16);
            pl[r] += __shfl_xor(pl[r], 4, 16);
            pl[r] += __shfl_xor(pl[r], 8, 16);
            l_run[r] = l_run[r] * alpha[r] + pl[r];
        }
        #pragma unroll
        for (int d = 0; d < 8; ++d)
            #pragma unroll
            for (int r = 0; r < 4; ++r)
                oacc[d][r] *= alpha[r];

        // ---- P: C-layout -> LDS -> A-layout (per-wave region, no barrier) ----
        short* pw = &p_lds[wave * 16 * PLD];
        #pragma unroll
        for (int nt = 0; nt < 4; ++nt)
            #pragma unroll
            for (int r = 0; r < 4; ++r)
                pw[(quad * 4 + r) * PLD + nt * 16 + l16] = pb[nt][r];

        bf16x8 pf[2];
        #pragma unroll
        for (int ks = 0; ks < 2; ++ks)
            pf[ks] = *(const bf16x8*)&pw[l16 * PLD + ks * 32 + quad * 8];

        // ---- O += P V ----
        #pragma unroll
        for (int d = 0; d < 8; ++d) {
            #pragma unroll
            for (int ks = 0; ks < 2; ++ks) {
                const bf16x8 vf =
                    *(const bf16x8*)&vt_lds[(d * 16 + l16) * VLD + ks * 32 + quad * 8];
                oacc[d] = __builtin_amdgcn_mfma_f32_16x16x32_bf16(pf[ks], vf, oacc[d], 0, 0, 0);
            }
        }
    }

    // ---- epilogue: normalize and store ----
    const int orow0 = q0 + wave * 16 + quad * 4;
    #pragma unroll
    for (int r = 0; r < 4; ++r) {
        const float inv = 1.0f / l_run[r];
        float* orow = outg + (size_t)(orow0 + r) * HD + l16;
        #pragma unroll
        for (int d = 0; d < 8; ++d)
            orow[d * 16] = oacc[d][r] * inv;
    }
}

extern "C" void kernel_launch(void* const* d_in, const int* in_sizes, int n_in,
                              void* d_out, int out_size, void* d_ws, size_t ws_size,
                              hipStream_t stream) {
    const float* q    = (const float*)d_in[0];
    const float* k    = (const float*)d_in[1];
    const float* v    = (const float*)d_in[2];
    const float* mask = (const float*)d_in[3];
    float* out = (float*)d_out;
    dim3 grid(S_LEN / BQ, 4 * 16);   // 32 q-tiles x 64 (b,h)
    fattn_kernel<<<grid, 256, 0, stream>>>(q, k, v, mask, out);
}

// Round 2
// 934.605 us; speedup vs baseline: 1.2461x; 1.2461x over previous
//
#include <hip/hip_runtime.h>

// Flash-attention fwd, B=4 H=16 S=2048 D=128, fp32 in/out, bf16 MFMA compute.
// Round 2: kill LDS bank conflicts.
//  - V staged transposed via in-register 8x4 transpose + ds_write_b128,
//    XOR swizzle (kk-block ^ (d>>2)&7) => writes AND reads at the 8-dword/bank
//    optimum (verified by enumeration for all dt/ks).
//  - P roundtrip: PLD=68 => scalar writes land 32 banks x 2 same-dword lanes
//    (free); reads as two ds_read_b64 at the 4-dword/bank minimum.
//  - K staging unchanged (already minimal).

#define S_LEN 2048
#define HD 128
#define BQ 64
#define BK 64
#define KLD 136   // K LDS row stride (hw): 68 dw/row -> frag reads 8 dw/bank (opt)
#define VLD 72    // V^T LDS row stride (hw): 36 dw/row + XOR swizzle -> optimal
#define PLD 68    // P LDS row stride (hw): 34 dw/row -> conflict-free

typedef __attribute__((ext_vector_type(8))) short bf16x8;
typedef __attribute__((ext_vector_type(4))) float f32x4;
typedef __attribute__((ext_vector_type(4))) short s16x4;

static __device__ __forceinline__ unsigned short f2bf(float f) {
    unsigned int u = __builtin_bit_cast(unsigned int, f);
    u += 0x7fffu + ((u >> 16) & 1u);   // round-to-nearest-even
    return (unsigned short)(u >> 16);
}

__global__ __launch_bounds__(256, 2)
void fattn_kernel(const float* __restrict__ qg0, const float* __restrict__ kg0,
                  const float* __restrict__ vg0, const float* __restrict__ maskg,
                  float* __restrict__ outg0)
{
    __shared__ short k_lds[BK * KLD];       // K tile, row-major [kk][d]
    __shared__ short vt_lds[HD * VLD];      // V tile, transposed [d][kk], kk-swizzled
    __shared__ short p_lds[4 * 16 * PLD];   // per-wave P tile [16][BK]

    const int tid  = threadIdx.x;
    const int wave = tid >> 6;
    const int lane = tid & 63;
    const int quad = lane >> 4;
    const int l16  = lane & 15;

    const int q0 = blockIdx.x * BQ;
    const int bh = blockIdx.y;

    const float* qg   = qg0 + (size_t)bh * S_LEN * HD;
    const float* kg   = kg0 + (size_t)bh * S_LEN * HD;
    const float* vg   = vg0 + (size_t)bh * S_LEN * HD;
    float*       outg = outg0 + (size_t)bh * S_LEN * HD;

    // Q A-fragments: m = l16, k = ks*32 + quad*8 + j  (held for whole kernel)
    bf16x8 qf[4];
    {
        const float* qrow = qg + (size_t)(q0 + wave * 16 + l16) * HD + quad * 8;
        #pragma unroll
        for (int ks = 0; ks < 4; ++ks)
            #pragma unroll
            for (int j = 0; j < 8; ++j)
                qf[ks][j] = (short)f2bf(qrow[ks * 32 + j]);
    }

    float m_run[4], l_run[4];
    f32x4 oacc[8];
    #pragma unroll
    for (int r = 0; r < 4; ++r) { m_run[r] = -3.0e38f; l_run[r] = 0.0f; }
    #pragma unroll
    for (int d = 0; d < 8; ++d) oacc[d] = (f32x4){0.f, 0.f, 0.f, 0.f};

    const float scale = 0.088388347648318447f;  // 1/sqrt(128)
    const float* mrow = maskg + (size_t)(q0 + wave * 16 + quad * 4) * S_LEN + l16;

    // staging decomposition
    const int rr = tid >> 5;          // 0..7
    const int cc = tid & 31;          // 0..31
    short* const pw = &p_lds[wave * 16 * PLD];

    for (int kt = 0; kt < S_LEN / BK; ++kt) {
        const int kbase = kt * BK;
        __syncthreads();   // previous iter's LDS reads done before restage

        // ---- stage K row-major: thread covers rows rr+8*it, cols 4cc..4cc+3 ----
        #pragma unroll
        for (int it = 0; it < 8; ++it) {
            const int row = rr + it * 8;
            const f32x4 kv4 = *(const f32x4*)(kg + (size_t)(kbase + row) * HD + cc * 4);
            s16x4 kb4;
            kb4[0] = (short)f2bf(kv4[0]); kb4[1] = (short)f2bf(kv4[1]);
            kb4[2] = (short)f2bf(kv4[2]); kb4[3] = (short)f2bf(kv4[3]);
            *(s16x4*)&k_lds[row * KLD + cc * 4] = kb4;
        }

        // ---- stage V transposed: thread loads rows 8rr..8rr+7, cols 4cc..4cc+3,
        //      transposes in registers, writes 4 x b128 (8 kk at one d) ----
        {
            f32x4 vr[8];
            #pragma unroll
            for (int it = 0; it < 8; ++it)
                vr[it] = *(const f32x4*)(vg + (size_t)(kbase + rr * 8 + it) * HD + cc * 4);
            #pragma unroll
            for (int i = 0; i < 4; ++i) {
                bf16x8 col;
                #pragma unroll
                for (int it = 0; it < 8; ++it)
                    col[it] = (short)f2bf(vr[it][i]);
                const int d = cc * 4 + i;
                const int pblk = rr ^ (cc & 7);   // swizzle: block ^ ((d>>2)&7), (d>>2)&7==cc&7
                *(bf16x8*)&vt_lds[d * VLD + pblk * 8] = col;
            }
        }
        __syncthreads();

        // ---- S = (Q K^T)*scale + mask ----
        f32x4 sf[4];
        #pragma unroll
        for (int nt = 0; nt < 4; ++nt) {
            f32x4 acc = (f32x4){0.f, 0.f, 0.f, 0.f};
            #pragma unroll
            for (int ks = 0; ks < 4; ++ks) {
                const bf16x8 kf =
                    *(const bf16x8*)&k_lds[(nt * 16 + l16) * KLD + ks * 32 + quad * 8];
                acc = __builtin_amdgcn_mfma_f32_16x16x32_bf16(qf[ks], kf, acc, 0, 0, 0);
            }
            sf[nt] = acc;
        }

        float sv[4][4];
        float mx[4] = {-3.0e38f, -3.0e38f, -3.0e38f, -3.0e38f};
        #pragma unroll
        for (int nt = 0; nt < 4; ++nt)
            #pragma unroll
            for (int r = 0; r < 4; ++r) {
                const float s = sf[nt][r] * scale + mrow[(size_t)r * S_LEN + kbase + nt * 16];
                sv[nt][r] = s;
                mx[r] = fmaxf(mx[r], s);
            }
        #pragma unroll
        for (int r = 0; r < 4; ++r) {
            mx[r] = fmaxf(mx[r], __shfl_xor(mx[r], 1, 16));
            mx[r] = fmaxf(mx[r], __shfl_xor(mx[r], 2, 16));
            mx[r] = fmaxf(mx[r], __shfl_xor(mx[r], 4, 16));
            mx[r] = fmaxf(mx[r], __shfl_xor(mx[r], 8, 16));
        }

        float alpha[4], pl[4];
        #pragma unroll
        for (int r = 0; r < 4; ++r) {
            const float mnew = fmaxf(m_run[r], mx[r]);
            alpha[r] = __expf(m_run[r] - mnew);
            m_run[r] = mnew;
            pl[r] = 0.f;
        }

        short pb[4][4];
        #pragma unroll
        for (int nt = 0; nt < 4; ++nt)
            #pragma unroll
            for (int r = 0; r < 4; ++r) {
                const float p = __expf(sv[nt][r] - m_run[r]);
                const unsigned short b = f2bf(p);
                pb[nt][r] = (short)b;
                // accumulate l from the *rounded* p so normalization matches PV
                pl[r] += __builtin_bit_cast(float, (unsigned int)b << 16);
            }
        #pragma unroll
        for (int r = 0; r < 4; ++r) {
            pl[r] += __shfl_xor(pl[r], 1, 16);
            pl[r] += __shfl_xor(pl[r], 2, 16);
            pl[r] += __shfl_xor(pl[r], 4, 16);
            pl[r] += __shfl_xor(pl[r], 8, 16);
            l_run[r] = l_run[r] * alpha[r] + pl[r];
        }
        #pragma unroll
        for (int d = 0; d < 8; ++d)
            #pragma unroll
            for (int r = 0; r < 4; ++r)
                oacc[d][r] *= alpha[r];

        // ---- P: C-layout -> LDS -> A-layout (per-wave region, no barrier) ----
        #pragma unroll
        for (int nt = 0; nt < 4; ++nt)
            #pragma unroll
            for (int r = 0; r < 4; ++r)
                pw[(quad * 4 + r) * PLD + nt * 16 + l16] = pb[nt][r];

        bf16x8 pf[2];
        #pragma unroll
        for (int ks = 0; ks < 2; ++ks) {
            const s16x4 lo = *(const s16x4*)&pw[l16 * PLD + ks * 32 + quad * 8];
            const s16x4 hi = *(const s16x4*)&pw[l16 * PLD + ks * 32 + quad * 8 + 4];
            pf[ks] = __builtin_shufflevector(lo, hi, 0, 1, 2, 3, 4, 5, 6, 7);
        }

        // ---- O += P V ----
        #pragma unroll
        for (int dt = 0; dt < 8; ++dt) {
            const int drow = dt * 16 + l16;
            const int tsw  = (drow >> 2) & 7;
            #pragma unroll
            for (int ks = 0; ks < 2; ++ks) {
                const bf16x8 vf =
                    *(const bf16x8*)&vt_lds[drow * VLD + (((4 * ks + quad) ^ tsw) * 8)];
                oacc[dt] = __builtin_amdgcn_mfma_f32_16x16x32_bf16(pf[ks], vf, oacc[dt], 0, 0, 0);
            }
        }
    }

    // ---- epilogue: normalize and store ----
    const int orow0 = q0 + wave * 16 + quad * 4;
    #pragma unroll
    for (int r = 0; r < 4; ++r) {
        const float inv = 1.0f / l_run[r];
        float* orow = outg + (size_t)(orow0 + r) * HD + l16;
        #pragma unroll
        for (int d = 0; d < 8; ++d)
            orow[d * 16] = oacc[d][r] * inv;
    }
}

extern "C" void kernel_launch(void* const* d_in, const int* in_sizes, int n_in,
                              void* d_out, int out_size, void* d_ws, size_t ws_size,
                              hipStream_t stream) {
    const float* q    = (const float*)d_in[0];
    const float* k    = (const float*)d_in[1];
    const float* v    = (const float*)d_in[2];
    const float* mask = (const float*)d_in[3];
    float* out = (float*)d_out;
    dim3 grid(S_LEN / BQ, 4 * 16);   // 32 q-tiles x 64 (b,h)
    fattn_kernel<<<grid, 256, 0, stream>>>(q, k, v, mask, out);
}

// Round 3
// 582.942 us; speedup vs baseline: 1.9978x; 1.6033x over previous
//
#include <hip/hip_runtime.h>

// Flash-attention fwd, B=4 H=16 S=2048 D=128, fp32 in/out, bf16 MFMA compute.
// Round 3: latency. (a) register-prefetch pipeline: K/V/mask global loads for
// tile kt+1 issued right after the staging barrier, held in VGPRs across the
// compute phase (global latency hidden by ~850 cyc of compute); LDS write
// phase consumes the registers. (b) grid swapped to (bh, qtile) so co-resident
// blocks share K/V (same bh) and mask slabs (same qtile) in L2/L3.

#define S_LEN 2048
#define HD 128
#define BQ 64
#define BK 64
#define NT (S_LEN / BK)
#define KLD 136   // K LDS row stride: frag reads 8 dw/bank (opt)
#define VLD 72    // V^T LDS row stride + XOR swizzle -> optimal
#define PLD 68    // P LDS row stride -> conflict-free

typedef __attribute__((ext_vector_type(8))) short bf16x8;
typedef __attribute__((ext_vector_type(4))) float f32x4;
typedef __attribute__((ext_vector_type(4))) short s16x4;

static __device__ __forceinline__ unsigned short f2bf(float f) {
    unsigned int u = __builtin_bit_cast(unsigned int, f);
    u += 0x7fffu + ((u >> 16) & 1u);   // round-to-nearest-even
    return (unsigned short)(u >> 16);
}

__global__ __launch_bounds__(256, 2)
void fattn_kernel(const float* __restrict__ qg0, const float* __restrict__ kg0,
                  const float* __restrict__ vg0, const float* __restrict__ maskg,
                  float* __restrict__ outg0)
{
    __shared__ short k_lds[BK * KLD];       // K tile, row-major [kk][d]
    __shared__ short vt_lds[HD * VLD];      // V tile, transposed [d][kk], kk-swizzled
    __shared__ short p_lds[4 * 16 * PLD];   // per-wave P tile [16][BK]

    const int tid  = threadIdx.x;
    const int wave = tid >> 6;
    const int lane = tid & 63;
    const int quad = lane >> 4;
    const int l16  = lane & 15;

    const int bh = blockIdx.x;              // fast dim: co-resident blocks share qtile
    const int q0 = blockIdx.y * BQ;

    const float* qg   = qg0 + (size_t)bh * S_LEN * HD;
    const float* kg   = kg0 + (size_t)bh * S_LEN * HD;
    const float* vg   = vg0 + (size_t)bh * S_LEN * HD;
    float*       outg = outg0 + (size_t)bh * S_LEN * HD;

    // Q A-fragments: m = l16, k = ks*32 + quad*8 + j  (held for whole kernel)
    bf16x8 qf[4];
    {
        const float* qrow = qg + (size_t)(q0 + wave * 16 + l16) * HD + quad * 8;
        #pragma unroll
        for (int ks = 0; ks < 4; ++ks) {
            const f32x4 a = *(const f32x4*)(qrow + ks * 32);
            const f32x4 b = *(const f32x4*)(qrow + ks * 32 + 4);
            #pragma unroll
            for (int j = 0; j < 4; ++j) {
                qf[ks][j]     = (short)f2bf(a[j]);
                qf[ks][j + 4] = (short)f2bf(b[j]);
            }
        }
    }

    float m_run[4], l_run[4];
    f32x4 oacc[8];
    #pragma unroll
    for (int r = 0; r < 4; ++r) { m_run[r] = -3.0e38f; l_run[r] = 0.0f; }
    #pragma unroll
    for (int d = 0; d < 8; ++d) oacc[d] = (f32x4){0.f, 0.f, 0.f, 0.f};

    const float scale = 0.088388347648318447f;  // 1/sqrt(128)
    const float* mrow = maskg + (size_t)(q0 + wave * 16 + quad * 4) * S_LEN + l16;

    const int rr = tid >> 5;          // 0..7
    const int cc = tid & 31;          // 0..31
    short* const pw = &p_lds[wave * 16 * PLD];

    // ---- prologue: prefetch tile 0 into registers ----
    f32x4 kpre[8], vpre[8];
    float mpre[4][4];
    #pragma unroll
    for (int it = 0; it < 8; ++it)
        kpre[it] = *(const f32x4*)(kg + (size_t)(rr + 8 * it) * HD + cc * 4);
    #pragma unroll
    for (int it = 0; it < 8; ++it)
        vpre[it] = *(const f32x4*)(vg + (size_t)(rr * 8 + it) * HD + cc * 4);
    #pragma unroll
    for (int nt = 0; nt < 4; ++nt)
        #pragma unroll
        for (int r = 0; r < 4; ++r)
            mpre[nt][r] = mrow[(size_t)r * S_LEN + nt * 16];

    for (int kt = 0; kt < NT; ++kt) {
        __syncthreads();   // previous iter's LDS reads done before restage

        // ---- LDS write phase: consume kpre/vpre (already resident) ----
        #pragma unroll
        for (int it = 0; it < 8; ++it) {
            s16x4 kb4;
            kb4[0] = (short)f2bf(kpre[it][0]); kb4[1] = (short)f2bf(kpre[it][1]);
            kb4[2] = (short)f2bf(kpre[it][2]); kb4[3] = (short)f2bf(kpre[it][3]);
            *(s16x4*)&k_lds[(rr + 8 * it) * KLD + cc * 4] = kb4;
        }
        #pragma unroll
        for (int i = 0; i < 4; ++i) {
            bf16x8 col;
            #pragma unroll
            for (int it = 0; it < 8; ++it)
                col[it] = (short)f2bf(vpre[it][i]);
            const int d = cc * 4 + i;
            const int pblk = rr ^ (cc & 7);   // swizzle: block ^ ((d>>2)&7)
            *(bf16x8*)&vt_lds[d * VLD + pblk * 8] = col;
        }
        __syncthreads();

        // ---- issue next tile's global loads; latency hidden by compute below ----
        const int nb = (kt + 1 < NT) ? (kt + 1) * BK : 0;   // wrap: harmless dummy
        #pragma unroll
        for (int it = 0; it < 8; ++it)
            kpre[it] = *(const f32x4*)(kg + (size_t)(nb + rr + 8 * it) * HD + cc * 4);
        #pragma unroll
        for (int it = 0; it < 8; ++it)
            vpre[it] = *(const f32x4*)(vg + (size_t)(nb + rr * 8 + it) * HD + cc * 4);

        // ---- S = (Q K^T)*scale + mask ----
        f32x4 sf[4];
        #pragma unroll
        for (int nt = 0; nt < 4; ++nt) {
            f32x4 acc = (f32x4){0.f, 0.f, 0.f, 0.f};
            #pragma unroll
            for (int ks = 0; ks < 4; ++ks) {
                const bf16x8 kf =
                    *(const bf16x8*)&k_lds[(nt * 16 + l16) * KLD + ks * 32 + quad * 8];
                acc = __builtin_amdgcn_mfma_f32_16x16x32_bf16(qf[ks], kf, acc, 0, 0, 0);
            }
            sf[nt] = acc;
        }

        float sv[4][4];
        float mx[4] = {-3.0e38f, -3.0e38f, -3.0e38f, -3.0e38f};
        #pragma unroll
        for (int nt = 0; nt < 4; ++nt)
            #pragma unroll
            for (int r = 0; r < 4; ++r) {
                const float s = sf[nt][r] * scale + mpre[nt][r];
                sv[nt][r] = s;
                mx[r] = fmaxf(mx[r], s);
            }

        // ---- prefetch next mask tile (mpre's last use was above) ----
        #pragma unroll
        for (int nt = 0; nt < 4; ++nt)
            #pragma unroll
            for (int r = 0; r < 4; ++r)
                mpre[nt][r] = mrow[(size_t)r * S_LEN + nb + nt * 16];

        #pragma unroll
        for (int r = 0; r < 4; ++r) {
            mx[r] = fmaxf(mx[r], __shfl_xor(mx[r], 1, 16));
            mx[r] = fmaxf(mx[r], __shfl_xor(mx[r], 2, 16));
            mx[r] = fmaxf(mx[r], __shfl_xor(mx[r], 4, 16));
            mx[r] = fmaxf(mx[r], __shfl_xor(mx[r], 8, 16));
        }

        float alpha[4], pl[4];
        #pragma unroll
        for (int r = 0; r < 4; ++r) {
            const float mnew = fmaxf(m_run[r], mx[r]);
            alpha[r] = __expf(m_run[r] - mnew);
            m_run[r] = mnew;
            pl[r] = 0.f;
        }

        short pb[4][4];
        #pragma unroll
        for (int nt = 0; nt < 4; ++nt)
            #pragma unroll
            for (int r = 0; r < 4; ++r) {
                const float p = __expf(sv[nt][r] - m_run[r]);
                const unsigned short b = f2bf(p);
                pb[nt][r] = (short)b;
                // accumulate l from the *rounded* p so normalization matches PV
                pl[r] += __builtin_bit_cast(float, (unsigned int)b << 16);
            }
        #pragma unroll
        for (int r = 0; r < 4; ++r) {
            pl[r] += __shfl_xor(pl[r], 1, 16);
            pl[r] += __shfl_xor(pl[r], 2, 16);
            pl[r] += __shfl_xor(pl[r], 4, 16);
            pl[r] += __shfl_xor(pl[r], 8, 16);
            l_run[r] = l_run[r] * alpha[r] + pl[r];
        }
        #pragma unroll
        for (int d = 0; d < 8; ++d)
            #pragma unroll
            for (int r = 0; r < 4; ++r)
                oacc[d][r] *= alpha[r];

        // ---- P: C-layout -> LDS -> A-layout (per-wave region, no barrier) ----
        #pragma unroll
        for (int nt = 0; nt < 4; ++nt)
            #pragma unroll
            for (int r = 0; r < 4; ++r)
                pw[(quad * 4 + r) * PLD + nt * 16 + l16] = pb[nt][r];

        bf16x8 pf[2];
        #pragma unroll
        for (int ks = 0; ks < 2; ++ks) {
            const s16x4 lo = *(const s16x4*)&pw[l16 * PLD + ks * 32 + quad * 8];
            const s16x4 hi = *(const s16x4*)&pw[l16 * PLD + ks * 32 + quad * 8 + 4];
            pf[ks] = __builtin_shufflevector(lo, hi, 0, 1, 2, 3, 4, 5, 6, 7);
        }

        // ---- O += P V ----
        #pragma unroll
        for (int dt = 0; dt < 8; ++dt) {
            const int drow = dt * 16 + l16;
            const int tsw  = (drow >> 2) & 7;
            #pragma unroll
            for (int ks = 0; ks < 2; ++ks) {
                const bf16x8 vf =
                    *(const bf16x8*)&vt_lds[drow * VLD + (((4 * ks + quad) ^ tsw) * 8)];
                oacc[dt] = __builtin_amdgcn_mfma_f32_16x16x32_bf16(pf[ks], vf, oacc[dt], 0, 0, 0);
            }
        }
    }

    // ---- epilogue: normalize and store ----
    const int orow0 = q0 + wave * 16 + quad * 4;
    #pragma unroll
    for (int r = 0; r < 4; ++r) {
        const float inv = 1.0f / l_run[r];
        float* orow = outg + (size_t)(orow0 + r) * HD + l16;
        #pragma unroll
        for (int d = 0; d < 8; ++d)
            orow[d * 16] = oacc[d][r] * inv;
    }
}

extern "C" void kernel_launch(void* const* d_in, const int* in_sizes, int n_in,
                              void* d_out, int out_size, void* d_ws, size_t ws_size,
                              hipStream_t stream) {
    const float* q    = (const float*)d_in[0];
    const float* k    = (const float*)d_in[1];
    const float* v    = (const float*)d_in[2];
    const float* mask = (const float*)d_in[3];
    float* out = (float*)d_out;
    dim3 grid(4 * 16, S_LEN / BQ);   // x = (b,h) fast, y = q-tile
    fattn_kernel<<<grid, 256, 0, stream>>>(q, k, v, mask, out);
}